// Round 7
// baseline (385.765 us; speedup 1.0000x reference)
//
#include <hip/hip_runtime.h>
#include <math.h>

#define NN   100000   // nodes
#define NE   1600000  // edges
#define IND  256      // input dim
#define HIDD 64       // hidden dim
#define OUTD 40       // output dim
#define COEF 0.1f     // 2*mu/p = 2*0.1/2.0

#define PSHIFT 8
#define PSIZE  256                        // nodes per partition
#define NPART  ((NN + PSIZE - 1) / PSIZE) // 391
#define SRCBITS 17                        // NN < 2^17; packed edge = (local_dst<<17)|src

#define CHUNK_A 4096      // edges per partition-pass block
#define PBLKS   ((NE + CHUNK_A - 1) / CHUNK_A)   // 391
#define W1TBLKS ((IND * HIDD + 255) / 256)       // 64

#define G1_TILES ((NN + 63) / 64)   // 1563 64-row tiles
#define G1_BLOCKS 512               // 2 per CU (64 KB LDS each)

typedef __attribute__((ext_vector_type(8))) short frag8;   // 8 bf16
typedef __attribute__((ext_vector_type(4))) float f32x4;

__device__ __forceinline__ unsigned short f2bf(float x) {  // RNE
    unsigned u = __float_as_uint(x);
    u += 0x7fffu + ((u >> 16) & 1u);
    return (unsigned short)(u >> 16);
}
__device__ __forceinline__ float bflo(unsigned v) { return __uint_as_float(v << 16); }
__device__ __forceinline__ float bfhi(unsigned v) { return __uint_as_float(v & 0xffff0000u); }

// ---- fused: per-partition edge counts (blocks < PBLKS) + W1 transpose (rest)
__global__ __launch_bounds__(256) void prep_kernel(const int* __restrict__ dst,
                                                   int* __restrict__ gcount,
                                                   const float* __restrict__ W1,
                                                   unsigned short* __restrict__ w1t) {
    int t = threadIdx.x;
    if (blockIdx.x >= PBLKS) {
        int i = (blockIdx.x - PBLKS) * 256 + t;
        if (i < IND * HIDD) {
            int k = i >> 6, n = i & 63;
            w1t[n * IND + k] = f2bf(W1[i]);
        }
        return;
    }
    __shared__ int cnt[NPART];
    for (int b = t; b < NPART; b += 256) cnt[b] = 0;
    __syncthreads();
    int base = blockIdx.x * CHUNK_A;
#pragma unroll
    for (int j = 0; j < 16; j++) {
        int e = base + j * 256 + t;
        if (e < NE) atomicAdd(&cnt[dst[e] >> PSHIFT], 1);
    }
    __syncthreads();
    for (int b = t; b < NPART; b += 256)
        if (cnt[b]) atomicAdd(&gcount[b], cnt[b]);
}

// ---- exclusive scan of 391 partition sums -> bscan[392] + gcursor + row_ptr[NN]
__global__ __launch_bounds__(512) void pscan_kernel(const int* __restrict__ gcount,
                                                    int* __restrict__ bscan,
                                                    int* __restrict__ gcursor,
                                                    int* __restrict__ row_ptr) {
    __shared__ int s[512];
    int t = threadIdx.x;
    int v = (t < NPART) ? gcount[t] : 0;
    s[t] = v;
    __syncthreads();
    for (int off = 1; off < 512; off <<= 1) {
        int xv = (t >= off) ? s[t - off] : 0;
        __syncthreads();
        s[t] += xv;
        __syncthreads();
    }
    int excl = s[t] - v;
    if (t < NPART) {
        bscan[t]   = excl;
        gcursor[t] = excl;
    }
    if (t == NPART - 1) {
        bscan[NPART] = excl + v;   // == NE
        row_ptr[NN]  = excl + v;
    }
}

// ---- bin edges by dst>>8 into partition-ordered packed ep: (local_dst<<17)|src
__global__ __launch_bounds__(256) void pfill_kernel(const int* __restrict__ src,
                                                    const int* __restrict__ dst,
                                                    int* __restrict__ gcursor,
                                                    unsigned* __restrict__ ep) {
    __shared__ int cnt[NPART];
    __shared__ int basep[NPART];
    int t = threadIdx.x;
    for (int b = t; b < NPART; b += 256) cnt[b] = 0;
    __syncthreads();
    int base = blockIdx.x * CHUNK_A;

    int v[16];
#pragma unroll
    for (int j = 0; j < 16; j++) {
        int e = base + j * 256 + t;
        v[j] = (e < NE) ? dst[e] : -1;
        if (v[j] >= 0) atomicAdd(&cnt[v[j] >> PSHIFT], 1);
    }
    __syncthreads();
    for (int b = t; b < NPART; b += 256) {
        int c = cnt[b];
        basep[b] = c ? atomicAdd(&gcursor[b], c) : 0;
        cnt[b] = 0;
    }
    __syncthreads();
#pragma unroll
    for (int j = 0; j < 16; j++) {
        int e = base + j * 256 + t;
        if (v[j] >= 0) {
            int p = v[j] >> PSHIFT;
            int pos = basep[p] + atomicAdd(&cnt[p], 1);
            ep[pos] = ((unsigned)(v[j] & (PSIZE - 1)) << SRCBITS) | (unsigned)src[e];
        }
    }
}

// ---- per-partition: LDS degree histogram, node quantities, 256-wide scan ->
// row_ptr, LDS-cursor scatter. 391 blocks x 256 threads (full CU spread).
__global__ __launch_bounds__(256) void fill3_kernel(const int* __restrict__ bscan,
                                                    const unsigned* __restrict__ ep,
                                                    int* __restrict__ row_ptr,
                                                    int* __restrict__ src_sorted,
                                                    float* __restrict__ dinv,
                                                    float* __restrict__ adinv,
                                                    float* __restrict__ beta) {
    __shared__ int cnt[PSIZE];
    __shared__ int scan[PSIZE];
    __shared__ int cursor[PSIZE];
    int p = blockIdx.x, t = threadIdx.x;
    int n0 = p << PSHIFT;
    int n = n0 + t;

    cnt[t] = 0;
    __syncthreads();
    int ebase = bscan[p];
    int eend  = bscan[p + 1];
    for (int e = ebase + t; e < eend; e += PSIZE)
        atomicAdd(&cnt[ep[e] >> SRCBITS], 1);
    __syncthreads();

    int d = cnt[t];
    if (n < NN) {
        float deg = (d > 0) ? (float)d : 1.0f;
        float di = rsqrtf(deg);
        dinv[n] = di;
        float denom = (float)d / deg + COEF;
        float a = 1.0f / denom;
        adinv[n] = a * di;
        beta[n]  = COEF * a;
    }

    scan[t] = d;
    __syncthreads();
    for (int off = 1; off < PSIZE; off <<= 1) {
        int x = (t >= off) ? scan[t - off] : 0;
        __syncthreads();
        scan[t] += x;
        __syncthreads();
    }
    int excl = scan[t] - d + ebase;
    if (n < NN) row_ptr[n] = excl;
    cursor[t] = excl;
    __syncthreads();

    for (int e = ebase + t; e < eend; e += PSIZE) {
        unsigned pk = ep[e];
        int pos = atomicAdd(&cursor[pk >> SRCBITS], 1);
        src_sorted[pos] = (int)(pk & ((1u << SRCBITS) - 1u));
    }
}

// ---------------------- h = relu(x @ W1 + b1), bf16 MFMA
// persistent blocks, double-buffered LDS, one-tile-ahead register prefetch.
__global__ __launch_bounds__(256, 2) void gemm1_kernel(const float* __restrict__ x,
                                                       const unsigned short* __restrict__ w1t,
                                                       const float* __restrict__ b1,
                                                       unsigned short* __restrict__ hb) {
    __shared__ unsigned short xs[2][64 * IND];   // 2 x 32 KB, swizzled
    int tid = threadIdx.x;
    int wave = tid >> 6, lane = tid & 63;
    int m = lane & 15, q = lane >> 4;

    float bias[4];
#pragma unroll
    for (int j = 0; j < 4; j++) bias[j] = b1[j * 16 + m];

    int lrow = wave * 16 + m;
    const char* xrow0 = (const char*)xs[0] + lrow * 512;
    const char* xrow1 = (const char*)xs[1] + lrow * 512;
    int swz = (lrow & 7) << 4;

    float4 v[16];
    int t = blockIdx.x;

#pragma unroll
    for (int i = 0; i < 16; i++) {
        int grow = t * 64 + i * 4 + wave;
        if (grow >= NN) grow = NN - 1;
        v[i] = *(const float4*)(x + (size_t)grow * IND + lane * 4);
    }

    int buf = 0;
    for (; t < G1_TILES; t += G1_BLOCKS) {
        unsigned short* xb = xs[buf];
#pragma unroll
        for (int i = 0; i < 16; i++) {
            int rr = i * 4 + wave;
            unsigned p0 = (unsigned)f2bf(v[i].x) | ((unsigned)f2bf(v[i].y) << 16);
            unsigned p1 = (unsigned)f2bf(v[i].z) | ((unsigned)f2bf(v[i].w) << 16);
            uint2 pk; pk.x = p0; pk.y = p1;
            int off = rr * 512 + ((lane * 8) ^ ((rr & 7) << 4));
            *(uint2*)((char*)xb + off) = pk;
        }

        int tn = t + G1_BLOCKS;
        if (tn < G1_TILES) {
#pragma unroll
            for (int i = 0; i < 16; i++) {
                int grow = tn * 64 + i * 4 + wave;
                if (grow >= NN) grow = NN - 1;
                v[i] = *(const float4*)(x + (size_t)grow * IND + lane * 4);
            }
        }

        __syncthreads();

        const char* xrow = buf ? xrow1 : xrow0;
        f32x4 acc[4] = {};
#pragma unroll
        for (int ks = 0; ks < 8; ks++) {
            frag8 a = *(const frag8*)(xrow + ((ks * 64 + q * 16) ^ swz));
#pragma unroll
            for (int j = 0; j < 4; j++) {
                frag8 b = *(const frag8*)(w1t + (j * 16 + m) * IND + ks * 32 + q * 8);
                acc[j] = __builtin_amdgcn_mfma_f32_16x16x32_bf16(a, b, acc[j], 0, 0, 0);
            }
        }

        int row0 = t * 64 + wave * 16;
#pragma unroll
        for (int j = 0; j < 4; j++) {
            int gcol = j * 16 + m;
#pragma unroll
            for (int r = 0; r < 4; r++) {
                int grow = row0 + q * 4 + r;
                if (grow < NN)
                    hb[(size_t)grow * HIDD + gcol] = f2bf(fmaxf(acc[j][r] + bias[j], 0.0f));
            }
        }
        buf ^= 1;
    }
}

// --- fn[i] = beta[i]*h[i] + adinv[i] * sum_e dinv[src_e] * f[src_e]  (bf16 CSR gather)
// 2-way unrolled edge loop + hoisted per-node loads.
__global__ __launch_bounds__(256) void gather_kernel(const int* __restrict__ row_ptr,
                                                     const int* __restrict__ src_sorted,
                                                     const float* __restrict__ dinv,
                                                     const float* __restrict__ adinv,
                                                     const unsigned short* __restrict__ fb,
                                                     const unsigned short* __restrict__ hb,
                                                     const float* __restrict__ beta,
                                                     unsigned short* __restrict__ fnb) {
    int wid = threadIdx.x >> 6, lane = threadIdx.x & 63;
    int node = blockIdx.x * 4 + wid;
    if (node >= NN) return;
    int base = row_ptr[node];
    int end  = row_ptr[node + 1];
    int g = lane >> 3, c = lane & 7;

    float an = adinv[node];
    float bt = beta[node];
    uint4 hv = ((const uint4*)hb)[(size_t)node * 8 + c];

    float acc[8];
#pragma unroll
    for (int i = 0; i < 8; i++) acc[i] = 0.f;

    int e = base + g;
    for (; e + 8 < end; e += 16) {
        int s0 = src_sorted[e];
        int s1 = src_sorted[e + 8];
        float w0 = dinv[s0];
        float w1 = dinv[s1];
        uint4 v0 = ((const uint4*)fb)[(size_t)s0 * 8 + c];
        uint4 v1 = ((const uint4*)fb)[(size_t)s1 * 8 + c];
        acc[0] += w0 * bflo(v0.x); acc[1] += w0 * bfhi(v0.x);
        acc[2] += w0 * bflo(v0.y); acc[3] += w0 * bfhi(v0.y);
        acc[4] += w0 * bflo(v0.z); acc[5] += w0 * bfhi(v0.z);
        acc[6] += w0 * bflo(v0.w); acc[7] += w0 * bfhi(v0.w);
        acc[0] += w1 * bflo(v1.x); acc[1] += w1 * bfhi(v1.x);
        acc[2] += w1 * bflo(v1.y); acc[3] += w1 * bfhi(v1.y);
        acc[4] += w1 * bflo(v1.z); acc[5] += w1 * bfhi(v1.z);
        acc[6] += w1 * bflo(v1.w); acc[7] += w1 * bfhi(v1.w);
    }
    if (e < end) {
        int s   = src_sorted[e];
        float w = dinv[s];
        uint4 v = ((const uint4*)fb)[(size_t)s * 8 + c];
        acc[0] += w * bflo(v.x); acc[1] += w * bfhi(v.x);
        acc[2] += w * bflo(v.y); acc[3] += w * bfhi(v.y);
        acc[4] += w * bflo(v.z); acc[5] += w * bfhi(v.z);
        acc[6] += w * bflo(v.w); acc[7] += w * bfhi(v.w);
    }
#pragma unroll
    for (int i = 0; i < 8; i++) {
        acc[i] += __shfl_xor(acc[i], 8);
        acc[i] += __shfl_xor(acc[i], 16);
        acc[i] += __shfl_xor(acc[i], 32);
    }

    if (g == 0) {
        float o[8];
        o[0] = an * acc[0] + bt * bflo(hv.x); o[1] = an * acc[1] + bt * bfhi(hv.x);
        o[2] = an * acc[2] + bt * bflo(hv.y); o[3] = an * acc[3] + bt * bfhi(hv.y);
        o[4] = an * acc[4] + bt * bflo(hv.z); o[5] = an * acc[5] + bt * bfhi(hv.z);
        o[6] = an * acc[6] + bt * bflo(hv.w); o[7] = an * acc[7] + bt * bfhi(hv.w);
        uint4 r;
        r.x = (unsigned)f2bf(o[0]) | ((unsigned)f2bf(o[1]) << 16);
        r.y = (unsigned)f2bf(o[2]) | ((unsigned)f2bf(o[3]) << 16);
        r.z = (unsigned)f2bf(o[4]) | ((unsigned)f2bf(o[5]) << 16);
        r.w = (unsigned)f2bf(o[6]) | ((unsigned)f2bf(o[7]) << 16);
        ((uint4*)fnb)[(size_t)node * 8 + c] = r;
    }
}

// --- fused iteration-2 gather + output head:
// f = beta*h + adinv * sum_e dinv[src]*fa[src]  (fp32, never materialized)
// out[node] = log_softmax(f @ W2 + b2)
// Per wave: one node. After the butterfly reduce every lane holds the fp32
// row slice for its c; g==0 lanes park the 64-dim row in a per-wave LDS
// strip, lanes j<40 do the matvec from LDS, 64-wide shuffles finish
// log-softmax. Saves fb write + fb re-read + one launch vs gather2+out.
__global__ __launch_bounds__(256) void gatherout_kernel(const int* __restrict__ row_ptr,
                                                        const int* __restrict__ src_sorted,
                                                        const float* __restrict__ dinv,
                                                        const float* __restrict__ adinv,
                                                        const unsigned short* __restrict__ fa,
                                                        const unsigned short* __restrict__ hb,
                                                        const float* __restrict__ beta,
                                                        const float* __restrict__ W2,
                                                        const float* __restrict__ b2,
                                                        float* __restrict__ out) {
    __shared__ float w2l[HIDD * OUTD];   // 10 KB, [k][j] row-major
    __shared__ float frow[4][HIDD];      // per-wave fp32 f row strip
    int tid = threadIdx.x;
    for (int i = tid; i < HIDD * OUTD; i += 256) w2l[i] = W2[i];
    __syncthreads();

    int wid = tid >> 6, lane = tid & 63;
    int node = blockIdx.x * 4 + wid;     // grid = 25000 exactly; node < NN always
    int base = row_ptr[node];
    int end  = row_ptr[node + 1];
    int g = lane >> 3, c = lane & 7;

    float an = adinv[node];
    float bt = beta[node];
    uint4 hv = ((const uint4*)hb)[(size_t)node * 8 + c];

    float acc[8];
#pragma unroll
    for (int i = 0; i < 8; i++) acc[i] = 0.f;

    int e = base + g;
    for (; e + 8 < end; e += 16) {
        int s0 = src_sorted[e];
        int s1 = src_sorted[e + 8];
        float w0 = dinv[s0];
        float w1 = dinv[s1];
        uint4 v0 = ((const uint4*)fa)[(size_t)s0 * 8 + c];
        uint4 v1 = ((const uint4*)fa)[(size_t)s1 * 8 + c];
        acc[0] += w0 * bflo(v0.x); acc[1] += w0 * bfhi(v0.x);
        acc[2] += w0 * bflo(v0.y); acc[3] += w0 * bfhi(v0.y);
        acc[4] += w0 * bflo(v0.z); acc[5] += w0 * bfhi(v0.z);
        acc[6] += w0 * bflo(v0.w); acc[7] += w0 * bfhi(v0.w);
        acc[0] += w1 * bflo(v1.x); acc[1] += w1 * bfhi(v1.x);
        acc[2] += w1 * bflo(v1.y); acc[3] += w1 * bfhi(v1.y);
        acc[4] += w1 * bflo(v1.z); acc[5] += w1 * bfhi(v1.z);
        acc[6] += w1 * bflo(v1.w); acc[7] += w1 * bfhi(v1.w);
    }
    if (e < end) {
        int s   = src_sorted[e];
        float w = dinv[s];
        uint4 v = ((const uint4*)fa)[(size_t)s * 8 + c];
        acc[0] += w * bflo(v.x); acc[1] += w * bfhi(v.x);
        acc[2] += w * bflo(v.y); acc[3] += w * bfhi(v.y);
        acc[4] += w * bflo(v.z); acc[5] += w * bfhi(v.z);
        acc[6] += w * bflo(v.w); acc[7] += w * bfhi(v.w);
    }
#pragma unroll
    for (int i = 0; i < 8; i++) {
        acc[i] += __shfl_xor(acc[i], 8);
        acc[i] += __shfl_xor(acc[i], 16);
        acc[i] += __shfl_xor(acc[i], 32);
    }

    if (g == 0) {   // deposit fp32 f row: dims 8c..8c+7
        frow[wid][c * 8 + 0] = an * acc[0] + bt * bflo(hv.x);
        frow[wid][c * 8 + 1] = an * acc[1] + bt * bfhi(hv.x);
        frow[wid][c * 8 + 2] = an * acc[2] + bt * bflo(hv.y);
        frow[wid][c * 8 + 3] = an * acc[3] + bt * bfhi(hv.y);
        frow[wid][c * 8 + 4] = an * acc[4] + bt * bflo(hv.z);
        frow[wid][c * 8 + 5] = an * acc[5] + bt * bfhi(hv.z);
        frow[wid][c * 8 + 6] = an * acc[6] + bt * bflo(hv.w);
        frow[wid][c * 8 + 7] = an * acc[7] + bt * bfhi(hv.w);
    }
    // wave-local LDS dependency; compiler inserts lgkmcnt. No cross-wave use.

    // ---- matvec + log_softmax (lanes 0..39 own output cols)
    float vj = (lane < OUTD) ? b2[lane] : -INFINITY;
    if (lane < OUTD) {
#pragma unroll 8
        for (int k = 0; k < HIDD; k++)
            vj += frow[wid][k] * w2l[k * OUTD + lane];
    }
    float mx = vj;
    mx = fmaxf(mx, __shfl_xor(mx, 1));
    mx = fmaxf(mx, __shfl_xor(mx, 2));
    mx = fmaxf(mx, __shfl_xor(mx, 4));
    mx = fmaxf(mx, __shfl_xor(mx, 8));
    mx = fmaxf(mx, __shfl_xor(mx, 16));
    mx = fmaxf(mx, __shfl_xor(mx, 32));
    float sm = (lane < OUTD) ? __expf(vj - mx) : 0.0f;
    sm += __shfl_xor(sm, 1);
    sm += __shfl_xor(sm, 2);
    sm += __shfl_xor(sm, 4);
    sm += __shfl_xor(sm, 8);
    sm += __shfl_xor(sm, 16);
    sm += __shfl_xor(sm, 32);
    float ls = mx + __logf(sm);
    if (lane < OUTD)
        out[(size_t)node * OUTD + lane] = vj - ls;
}

// ----------------------------------------------------------------------------
static inline size_t align256(size_t x) { return (x + 255) & ~(size_t)255; }

extern "C" void kernel_launch(void* const* d_in, const int* in_sizes, int n_in,
                              void* d_out, int out_size, void* d_ws, size_t ws_size,
                              hipStream_t stream) {
    const float* x  = (const float*)d_in[0];
    const int*   ei = (const int*)d_in[1];
    const float* W1 = (const float*)d_in[2];
    const float* b1 = (const float*)d_in[3];
    const float* W2 = (const float*)d_in[4];
    const float* b2 = (const float*)d_in[5];
    float* out = (float*)d_out;

    const int* src = ei;        // edge_index[0]
    const int* dst = ei + NE;   // edge_index[1]

    char* ws = (char*)d_ws;
    size_t off = 0;
    float* dinv     = (float*)(ws + off); off += align256((size_t)NN * 4);
    float* adinv    = (float*)(ws + off); off += align256((size_t)NN * 4);
    float* beta     = (float*)(ws + off); off += align256((size_t)NN * 4);
    int*   row_ptr  = (int*)(ws + off);   off += align256((size_t)(NN + 1) * 4);
    int*   gcount   = (int*)(ws + off);   off += align256((size_t)NPART * 4);
    int*   bscan    = (int*)(ws + off);   off += align256((size_t)(NPART + 1) * 4);
    int*   gcursor  = (int*)(ws + off);   off += align256((size_t)NPART * 4);
    int*   src_sorted = (int*)(ws + off); off += align256((size_t)NE * 4);
    unsigned* ep    = (unsigned*)(ws + off); off += align256((size_t)NE * 4);
    unsigned short* w1t = (unsigned short*)(ws + off); off += align256((size_t)IND * HIDD * 2);
    unsigned short* hb = (unsigned short*)(ws + off); off += align256((size_t)NN * HIDD * 2);
    unsigned short* fa = (unsigned short*)(ws + off); off += align256((size_t)NN * HIDD * 2);

    hipMemsetAsync(gcount, 0, (size_t)NPART * 4, stream);

    prep_kernel<<<PBLKS + W1TBLKS, 256, 0, stream>>>(dst, gcount, W1, w1t);
    pscan_kernel<<<1, 512, 0, stream>>>(gcount, bscan, gcursor, row_ptr);
    pfill_kernel<<<PBLKS, 256, 0, stream>>>(src, dst, gcursor, ep);
    fill3_kernel<<<NPART, 256, 0, stream>>>(bscan, ep, row_ptr, src_sorted,
                                            dinv, adinv, beta);

    gemm1_kernel<<<G1_BLOCKS, 256, 0, stream>>>(x, w1t, b1, hb);

    // iteration 1: fa = beta*h + A h
    gather_kernel<<<(NN + 3) / 4, 256, 0, stream>>>(row_ptr, src_sorted, dinv, adinv,
                                                    hb, hb, beta, fa);
    // iteration 2 fused with output head: out = log_softmax((beta*h + A fa) @ W2 + b2)
    gatherout_kernel<<<(NN + 3) / 4, 256, 0, stream>>>(row_ptr, src_sorted, dinv, adinv,
                                                       fa, hb, beta, W2, b2, out);
}

// Round 8
// 335.198 us; speedup vs baseline: 1.1509x; 1.1509x over previous
//
#include <hip/hip_runtime.h>
#include <math.h>

#define NN   100000   // nodes
#define NE   1600000  // edges
#define IND  256      // input dim
#define HIDD 64       // hidden dim
#define OUTD 40       // output dim
#define COEF 0.1f     // 2*mu/p = 2*0.1/2.0

#define PSHIFT 8
#define PSIZE  256                        // nodes per partition
#define NPART  ((NN + PSIZE - 1) / PSIZE) // 391
#define SRCBITS 17                        // NN < 2^17; packed edge = (local_dst<<17)|src

#define CHUNK_A 4096      // edges per partition-pass block
#define PBLKS   ((NE + CHUNK_A - 1) / CHUNK_A)   // 391
#define W1TBLKS ((IND * HIDD + 255) / 256)       // 64

#define G1_TILES ((NN + 63) / 64)   // 1563 64-row tiles
#define G1_BLOCKS 512               // gemm1 role blocks in fused fg_kernel

typedef __attribute__((ext_vector_type(8))) short frag8;   // 8 bf16
typedef __attribute__((ext_vector_type(4))) float f32x4;

__device__ __forceinline__ unsigned short f2bf(float x) {  // RNE
    unsigned u = __float_as_uint(x);
    u += 0x7fffu + ((u >> 16) & 1u);
    return (unsigned short)(u >> 16);
}
__device__ __forceinline__ float bflo(unsigned v) { return __uint_as_float(v << 16); }
__device__ __forceinline__ float bfhi(unsigned v) { return __uint_as_float(v & 0xffff0000u); }

// ---- fused: per-partition edge counts (blocks < PBLKS) + W1 transpose (rest)
__global__ __launch_bounds__(256) void prep_kernel(const int* __restrict__ dst,
                                                   int* __restrict__ gcount,
                                                   const float* __restrict__ W1,
                                                   unsigned short* __restrict__ w1t) {
    int t = threadIdx.x;
    if (blockIdx.x >= PBLKS) {
        int i = (blockIdx.x - PBLKS) * 256 + t;
        if (i < IND * HIDD) {
            int k = i >> 6, n = i & 63;
            w1t[n * IND + k] = f2bf(W1[i]);
        }
        return;
    }
    __shared__ int cnt[NPART];
    for (int b = t; b < NPART; b += 256) cnt[b] = 0;
    __syncthreads();
    int base = blockIdx.x * CHUNK_A;
#pragma unroll
    for (int j = 0; j < 16; j++) {
        int e = base + j * 256 + t;
        if (e < NE) atomicAdd(&cnt[dst[e] >> PSHIFT], 1);
    }
    __syncthreads();
    for (int b = t; b < NPART; b += 256)
        if (cnt[b]) atomicAdd(&gcount[b], cnt[b]);
}

// ---- exclusive scan of 391 partition sums -> bscan[392] + gcursor + row_ptr[NN]
__global__ __launch_bounds__(512) void pscan_kernel(const int* __restrict__ gcount,
                                                    int* __restrict__ bscan,
                                                    int* __restrict__ gcursor,
                                                    int* __restrict__ row_ptr) {
    __shared__ int s[512];
    int t = threadIdx.x;
    int v = (t < NPART) ? gcount[t] : 0;
    s[t] = v;
    __syncthreads();
    for (int off = 1; off < 512; off <<= 1) {
        int xv = (t >= off) ? s[t - off] : 0;
        __syncthreads();
        s[t] += xv;
        __syncthreads();
    }
    int excl = s[t] - v;
    if (t < NPART) {
        bscan[t]   = excl;
        gcursor[t] = excl;
    }
    if (t == NPART - 1) {
        bscan[NPART] = excl + v;   // == NE
        row_ptr[NN]  = excl + v;
    }
}

// ---- bin edges by dst>>8 into partition-ordered packed ep: (local_dst<<17)|src
__global__ __launch_bounds__(256) void pfill_kernel(const int* __restrict__ src,
                                                    const int* __restrict__ dst,
                                                    int* __restrict__ gcursor,
                                                    unsigned* __restrict__ ep) {
    __shared__ int cnt[NPART];
    __shared__ int basep[NPART];
    int t = threadIdx.x;
    for (int b = t; b < NPART; b += 256) cnt[b] = 0;
    __syncthreads();
    int base = blockIdx.x * CHUNK_A;

    int v[16];
#pragma unroll
    for (int j = 0; j < 16; j++) {
        int e = base + j * 256 + t;
        v[j] = (e < NE) ? dst[e] : -1;
        if (v[j] >= 0) atomicAdd(&cnt[v[j] >> PSHIFT], 1);
    }
    __syncthreads();
    for (int b = t; b < NPART; b += 256) {
        int c = cnt[b];
        basep[b] = c ? atomicAdd(&gcursor[b], c) : 0;
        cnt[b] = 0;
    }
    __syncthreads();
#pragma unroll
    for (int j = 0; j < 16; j++) {
        int e = base + j * 256 + t;
        if (v[j] >= 0) {
            int p = v[j] >> PSHIFT;
            int pos = basep[p] + atomicAdd(&cnt[p], 1);
            ep[pos] = ((unsigned)(v[j] & (PSIZE - 1)) << SRCBITS) | (unsigned)src[e];
        }
    }
}

// ---- fused fill3 (blocks 0..NPART-1) + gemm1 (dynamic-tile persistent blocks).
// Independent stages: fill3 consumes ep/bscan -> CSR + node quantities;
// gemm1 consumes x/w1t/b1 -> hb. Role-split lets gemm1 tiles run on CUs
// while fill3 blocks drain; dynamic tile counter (tilectr) makes freed CUs
// pick up remaining tiles (static striding would serialize the tail).
__global__ __launch_bounds__(256, 2) void fg_kernel(const int* __restrict__ bscan,
                                                    const unsigned* __restrict__ ep,
                                                    int* __restrict__ row_ptr,
                                                    int* __restrict__ src_sorted,
                                                    float* __restrict__ dinv,
                                                    float* __restrict__ adinv,
                                                    float* __restrict__ beta,
                                                    const float* __restrict__ x,
                                                    const unsigned short* __restrict__ w1t,
                                                    const float* __restrict__ b1,
                                                    unsigned short* __restrict__ hb,
                                                    int* __restrict__ tilectr) {
    __shared__ unsigned short xs[2][64 * IND];   // 64 KB (gemm1 role)
    __shared__ int cnt[PSIZE];                   // fill3 role (3 KB)
    __shared__ int scan[PSIZE];
    __shared__ int cursor[PSIZE];
    __shared__ int tsh;                          // broadcast next tile
    int tid = threadIdx.x;

    if (blockIdx.x < NPART) {
        // ---------------- fill3 role ----------------
        int p = blockIdx.x, t = tid;
        int n0 = p << PSHIFT;
        int n = n0 + t;

        cnt[t] = 0;
        __syncthreads();
        int ebase = bscan[p];
        int eend  = bscan[p + 1];
        for (int e = ebase + t; e < eend; e += PSIZE)
            atomicAdd(&cnt[ep[e] >> SRCBITS], 1);
        __syncthreads();

        int d = cnt[t];
        if (n < NN) {
            float deg = (d > 0) ? (float)d : 1.0f;
            float di = rsqrtf(deg);
            dinv[n] = di;
            float denom = (float)d / deg + COEF;
            float a = 1.0f / denom;
            adinv[n] = a * di;
            beta[n]  = COEF * a;
        }

        scan[t] = d;
        __syncthreads();
        for (int off = 1; off < PSIZE; off <<= 1) {
            int xv = (t >= off) ? scan[t - off] : 0;
            __syncthreads();
            scan[t] += xv;
            __syncthreads();
        }
        int excl = scan[t] - d + ebase;
        if (n < NN) row_ptr[n] = excl;
        cursor[t] = excl;
        __syncthreads();

        for (int e = ebase + t; e < eend; e += PSIZE) {
            unsigned pk = ep[e];
            int pos = atomicAdd(&cursor[pk >> SRCBITS], 1);
            src_sorted[pos] = (int)(pk & ((1u << SRCBITS) - 1u));
        }
        return;
    }

    // ---------------- gemm1 role (dynamic tiles) ----------------
    int wave = tid >> 6, lane = tid & 63;
    int m = lane & 15, q = lane >> 4;

    float bias[4];
#pragma unroll
    for (int j = 0; j < 4; j++) bias[j] = b1[j * 16 + m];

    int lrow = wave * 16 + m;
    const char* xrow0 = (const char*)xs[0] + lrow * 512;
    const char* xrow1 = (const char*)xs[1] + lrow * 512;
    int swz = (lrow & 7) << 4;

    if (tid == 0) tsh = atomicAdd(tilectr, 1);
    __syncthreads();
    int t = tsh;
    if (t >= G1_TILES) return;

    float4 v[16];
#pragma unroll
    for (int i = 0; i < 16; i++) {
        int grow = t * 64 + i * 4 + wave;
        if (grow >= NN) grow = NN - 1;
        v[i] = *(const float4*)(x + (size_t)grow * IND + lane * 4);
    }

    int buf = 0;
    while (true) {
        if (tid == 0) tsh = atomicAdd(tilectr, 1);

        // convert + swizzled ds_write of tile t
        unsigned short* xb = xs[buf];
#pragma unroll
        for (int i = 0; i < 16; i++) {
            int rr = i * 4 + wave;
            unsigned p0 = (unsigned)f2bf(v[i].x) | ((unsigned)f2bf(v[i].y) << 16);
            unsigned p1 = (unsigned)f2bf(v[i].z) | ((unsigned)f2bf(v[i].w) << 16);
            uint2 pk; pk.x = p0; pk.y = p1;
            int off = rr * 512 + ((lane * 8) ^ ((rr & 7) << 4));
            *(uint2*)((char*)xb + off) = pk;
        }

        __syncthreads();   // xs[buf] + tsh visible to all waves
        int tn = tsh;

        if (tn < G1_TILES) {   // issue next tile's loads; in flight across MFMA
#pragma unroll
            for (int i = 0; i < 16; i++) {
                int grow = tn * 64 + i * 4 + wave;
                if (grow >= NN) grow = NN - 1;
                v[i] = *(const float4*)(x + (size_t)grow * IND + lane * 4);
            }
        }

        const char* xrow = buf ? xrow1 : xrow0;
        f32x4 acc[4] = {};
#pragma unroll
        for (int ks = 0; ks < 8; ks++) {
            frag8 a = *(const frag8*)(xrow + ((ks * 64 + q * 16) ^ swz));
#pragma unroll
            for (int j = 0; j < 4; j++) {
                frag8 b = *(const frag8*)(w1t + (j * 16 + m) * IND + ks * 32 + q * 8);
                acc[j] = __builtin_amdgcn_mfma_f32_16x16x32_bf16(a, b, acc[j], 0, 0, 0);
            }
        }

        int row0 = t * 64 + wave * 16;
#pragma unroll
        for (int j = 0; j < 4; j++) {
            int gcol = j * 16 + m;
#pragma unroll
            for (int r = 0; r < 4; r++) {
                int grow = row0 + q * 4 + r;
                if (grow < NN)
                    hb[(size_t)grow * HIDD + gcol] = f2bf(fmaxf(acc[j][r] + bias[j], 0.0f));
            }
        }
        buf ^= 1;
        if (tn >= G1_TILES) break;
        t = tn;
        // single barrier per iter: buffer written at iter k+2 is separated
        // from its read at iter k by the barrier at k+1.
    }
}

// --- fn[i] = beta[i]*h[i] + adinv[i] * sum_e dinv[src_e] * f[src_e]  (bf16 CSR gather)
// 2-way unrolled edge loop + hoisted per-node loads.
__global__ __launch_bounds__(256) void gather_kernel(const int* __restrict__ row_ptr,
                                                     const int* __restrict__ src_sorted,
                                                     const float* __restrict__ dinv,
                                                     const float* __restrict__ adinv,
                                                     const unsigned short* __restrict__ fb,
                                                     const unsigned short* __restrict__ hb,
                                                     const float* __restrict__ beta,
                                                     unsigned short* __restrict__ fnb) {
    int wid = threadIdx.x >> 6, lane = threadIdx.x & 63;
    int node = blockIdx.x * 4 + wid;
    if (node >= NN) return;
    int base = row_ptr[node];
    int end  = row_ptr[node + 1];
    int g = lane >> 3, c = lane & 7;

    float an = adinv[node];
    float bt = beta[node];
    uint4 hv = ((const uint4*)hb)[(size_t)node * 8 + c];

    float acc[8];
#pragma unroll
    for (int i = 0; i < 8; i++) acc[i] = 0.f;

    int e = base + g;
    for (; e + 8 < end; e += 16) {
        int s0 = src_sorted[e];
        int s1 = src_sorted[e + 8];
        float w0 = dinv[s0];
        float w1 = dinv[s1];
        uint4 v0 = ((const uint4*)fb)[(size_t)s0 * 8 + c];
        uint4 v1 = ((const uint4*)fb)[(size_t)s1 * 8 + c];
        acc[0] += w0 * bflo(v0.x); acc[1] += w0 * bfhi(v0.x);
        acc[2] += w0 * bflo(v0.y); acc[3] += w0 * bfhi(v0.y);
        acc[4] += w0 * bflo(v0.z); acc[5] += w0 * bfhi(v0.z);
        acc[6] += w0 * bflo(v0.w); acc[7] += w0 * bfhi(v0.w);
        acc[0] += w1 * bflo(v1.x); acc[1] += w1 * bfhi(v1.x);
        acc[2] += w1 * bflo(v1.y); acc[3] += w1 * bfhi(v1.y);
        acc[4] += w1 * bflo(v1.z); acc[5] += w1 * bfhi(v1.z);
        acc[6] += w1 * bflo(v1.w); acc[7] += w1 * bfhi(v1.w);
    }
    if (e < end) {
        int s   = src_sorted[e];
        float w = dinv[s];
        uint4 v = ((const uint4*)fb)[(size_t)s * 8 + c];
        acc[0] += w * bflo(v.x); acc[1] += w * bfhi(v.x);
        acc[2] += w * bflo(v.y); acc[3] += w * bfhi(v.y);
        acc[4] += w * bflo(v.z); acc[5] += w * bfhi(v.z);
        acc[6] += w * bflo(v.w); acc[7] += w * bfhi(v.w);
    }
#pragma unroll
    for (int i = 0; i < 8; i++) {
        acc[i] += __shfl_xor(acc[i], 8);
        acc[i] += __shfl_xor(acc[i], 16);
        acc[i] += __shfl_xor(acc[i], 32);
    }

    if (g == 0) {
        float o[8];
        o[0] = an * acc[0] + bt * bflo(hv.x); o[1] = an * acc[1] + bt * bfhi(hv.x);
        o[2] = an * acc[2] + bt * bflo(hv.y); o[3] = an * acc[3] + bt * bfhi(hv.y);
        o[4] = an * acc[4] + bt * bflo(hv.z); o[5] = an * acc[5] + bt * bfhi(hv.z);
        o[6] = an * acc[6] + bt * bflo(hv.w); o[7] = an * acc[7] + bt * bfhi(hv.w);
        uint4 r;
        r.x = (unsigned)f2bf(o[0]) | ((unsigned)f2bf(o[1]) << 16);
        r.y = (unsigned)f2bf(o[2]) | ((unsigned)f2bf(o[3]) << 16);
        r.z = (unsigned)f2bf(o[4]) | ((unsigned)f2bf(o[5]) << 16);
        r.w = (unsigned)f2bf(o[6]) | ((unsigned)f2bf(o[7]) << 16);
        ((uint4*)fnb)[(size_t)node * 8 + c] = r;
    }
}

// ------------------- out = log_softmax(f @ W2 + b2), bf16 MFMA
__global__ __launch_bounds__(256) void out_kernel(const unsigned short* __restrict__ fb,
                                                  const float* __restrict__ W2,
                                                  const float* __restrict__ b2,
                                                  float* __restrict__ out) {
    __shared__ float w2l[HIDD * OUTD];   // raw W2, 10 KB
    int tid = threadIdx.x;
    for (int i = tid; i < HIDD * OUTD; i += 256) w2l[i] = W2[i];
    __syncthreads();

    int wave = tid >> 6, lane = tid & 63;
    int m = lane & 15, q = lane >> 4;

    frag8 bfr[3][2];
    float bias[3];
#pragma unroll
    for (int j = 0; j < 3; j++) {
        int n = j * 16 + m;
        bias[j] = (n < OUTD) ? b2[n] : 0.0f;
#pragma unroll
        for (int s = 0; s < 2; s++) {
            short tmp[8];
#pragma unroll
            for (int i = 0; i < 8; i++) {
                int k = s * 32 + q * 8 + i;
                float w = (n < OUTD) ? w2l[k * OUTD + n] : 0.0f;
                tmp[i] = (short)f2bf(w);
            }
            bfr[j][s] = *(frag8*)tmp;
        }
    }

    int block0 = blockIdx.x * 256;
    for (int t = 0; t < 4; t++) {
        int row0 = block0 + wave * 64 + t * 16;
        if (row0 >= NN) break;
        int arow = row0 + m;
        if (arow >= NN) arow = NN - 1;
        const frag8* ap = (const frag8*)(fb + (size_t)arow * HIDD);
        frag8 a0 = ap[q];
        frag8 a1 = ap[4 + q];

        f32x4 acc[3] = {};
#pragma unroll
        for (int j = 0; j < 3; j++) {
            acc[j] = __builtin_amdgcn_mfma_f32_16x16x32_bf16(a0, bfr[j][0], acc[j], 0, 0, 0);
            acc[j] = __builtin_amdgcn_mfma_f32_16x16x32_bf16(a1, bfr[j][1], acc[j], 0, 0, 0);
        }

#pragma unroll
        for (int r = 0; r < 4; r++) {
            int orow = row0 + q * 4 + r;
            float v0 = acc[0][r] + bias[0];
            float v1 = acc[1][r] + bias[1];
            float v2 = (m < 8) ? (acc[2][r] + bias[2]) : -INFINITY;
            float mx = fmaxf(fmaxf(v0, v1), v2);
            mx = fmaxf(mx, __shfl_xor(mx, 1));
            mx = fmaxf(mx, __shfl_xor(mx, 2));
            mx = fmaxf(mx, __shfl_xor(mx, 4));
            mx = fmaxf(mx, __shfl_xor(mx, 8));
            float sum = __expf(v0 - mx) + __expf(v1 - mx) + ((m < 8) ? __expf(v2 - mx) : 0.0f);
            sum += __shfl_xor(sum, 1);
            sum += __shfl_xor(sum, 2);
            sum += __shfl_xor(sum, 4);
            sum += __shfl_xor(sum, 8);
            float ls = mx + __logf(sum);
            if (orow < NN) {
                float* orow_p = out + (size_t)orow * OUTD;
                orow_p[m]      = v0 - ls;
                orow_p[16 + m] = v1 - ls;
                if (m < 8) orow_p[32 + m] = v2 - ls;
            }
        }
    }
}

// ----------------------------------------------------------------------------
static inline size_t align256(size_t x) { return (x + 255) & ~(size_t)255; }

extern "C" void kernel_launch(void* const* d_in, const int* in_sizes, int n_in,
                              void* d_out, int out_size, void* d_ws, size_t ws_size,
                              hipStream_t stream) {
    const float* x  = (const float*)d_in[0];
    const int*   ei = (const int*)d_in[1];
    const float* W1 = (const float*)d_in[2];
    const float* b1 = (const float*)d_in[3];
    const float* W2 = (const float*)d_in[4];
    const float* b2 = (const float*)d_in[5];
    float* out = (float*)d_out;

    const int* src = ei;        // edge_index[0]
    const int* dst = ei + NE;   // edge_index[1]

    char* ws = (char*)d_ws;
    size_t off = 0;
    float* dinv     = (float*)(ws + off); off += align256((size_t)NN * 4);
    float* adinv    = (float*)(ws + off); off += align256((size_t)NN * 4);
    float* beta     = (float*)(ws + off); off += align256((size_t)NN * 4);
    int*   row_ptr  = (int*)(ws + off);   off += align256((size_t)(NN + 1) * 4);
    int*   gcount   = (int*)(ws + off);   off += align256((size_t)(NPART + 64) * 4);
    int*   tilectr  = gcount + NPART;     // zeroed by the same memset
    int*   bscan    = (int*)(ws + off);   off += align256((size_t)(NPART + 1) * 4);
    int*   gcursor  = (int*)(ws + off);   off += align256((size_t)NPART * 4);
    int*   src_sorted = (int*)(ws + off); off += align256((size_t)NE * 4);
    unsigned* ep    = (unsigned*)(ws + off); off += align256((size_t)NE * 4);
    unsigned short* w1t = (unsigned short*)(ws + off); off += align256((size_t)IND * HIDD * 2);
    unsigned short* hb = (unsigned short*)(ws + off); off += align256((size_t)NN * HIDD * 2);
    unsigned short* fa = (unsigned short*)(ws + off); off += align256((size_t)NN * HIDD * 2);
    unsigned short* fb = (unsigned short*)(ws + off); off += align256((size_t)NN * HIDD * 2);

    hipMemsetAsync(gcount, 0, (size_t)(NPART + 64) * 4, stream);

    prep_kernel<<<PBLKS + W1TBLKS, 256, 0, stream>>>(dst, gcount, W1, w1t);
    pscan_kernel<<<1, 512, 0, stream>>>(gcount, bscan, gcursor, row_ptr);
    pfill_kernel<<<PBLKS, 256, 0, stream>>>(src, dst, gcursor, ep);

    // fused fill3 + gemm1 (independent stages, role-split blocks, dynamic tiles)
    fg_kernel<<<NPART + G1_BLOCKS, 256, 0, stream>>>(bscan, ep, row_ptr, src_sorted,
                                                     dinv, adinv, beta,
                                                     x, w1t, b1, hb, tilectr);

    // iteration 1: fa = beta*h + A h
    gather_kernel<<<(NN + 3) / 4, 256, 0, stream>>>(row_ptr, src_sorted, dinv, adinv,
                                                    hb, hb, beta, fa);
    // iteration 2: fb = beta*h + A fa
    gather_kernel<<<(NN + 3) / 4, 256, 0, stream>>>(row_ptr, src_sorted, dinv, adinv,
                                                    fa, hb, beta, fb);

    out_kernel<<<(NN + 255) / 256, 256, 0, stream>>>(fb, W2, b2, out);
}